// Round 2
// baseline (508.894 us; speedup 1.0000x reference)
//
#include <hip/hip_runtime.h>
#include <cstdint>
#include <type_traits>
#include <utility>

// ---------------------------------------------------------------------------
// SOARALinearLayer: out = x @ (W_deq + B2@A2)^T + bias
//   where A2 = lora_A @ R_v  (fold input butterfly into A)
//         B2 = R_u @ lora_B  (fold output butterfly into B), scaled by ALPHA/RANK
// Entire op becomes one bf16 MFMA GEMM (M=8192, N=4096, K=4096) + tiny prep.
// ---------------------------------------------------------------------------

typedef unsigned short u16;
typedef unsigned int   u32;
typedef short  s16x8 __attribute__((ext_vector_type(8)));
typedef __bf16 b16x8 __attribute__((ext_vector_type(8)));
typedef float  f32x4 __attribute__((ext_vector_type(4)));
typedef int    i32x4 __attribute__((ext_vector_type(4)));

#define D_IN  4096
#define D_OUT 4096
#define M_TOK 8192
#define RANK  32
#define SCALING 1.0f   /* ALPHA/RANK = 32/32 */

// ---- bf16 round-to-nearest-even ----
__device__ __forceinline__ u16 f2bf(float f) {
  u32 u = __builtin_bit_cast(u32, f);
  u += 0x7FFFu + ((u >> 16) & 1u);
  return (u16)(u >> 16);
}

// ---- MFMA wrapper: handle both i16-vector and __bf16-vector builtin sigs ----
template <typename T, typename = void>
struct mfma_takes_i16 : std::false_type {};
template <typename T>
struct mfma_takes_i16<T, std::void_t<decltype(__builtin_amdgcn_mfma_f32_16x16x32_bf16(
    std::declval<T>(), std::declval<T>(), std::declval<f32x4>(), 0, 0, 0))>>
    : std::true_type {};

template <typename T>
__device__ __forceinline__ f32x4 mfma_bf16(T a, T b, f32x4 c) {
  if constexpr (mfma_takes_i16<T>::value) {
    return __builtin_amdgcn_mfma_f32_16x16x32_bf16(a, b, c, 0, 0, 0);
  } else {
    return __builtin_amdgcn_mfma_f32_16x16x32_bf16(
        __builtin_bit_cast(b16x8, a), __builtin_bit_cast(b16x8, b), c, 0, 0, 0);
  }
}

// ---- async global->LDS, 16B per lane ----
__device__ __forceinline__ void gload_lds16(const void* g, void* l) {
  __builtin_amdgcn_global_load_lds((const __attribute__((address_space(1))) u32*)g,
                                   (__attribute__((address_space(3))) u32*)l,
                                   16, 0, 0);
}

// ===========================================================================
// Kernel 1: A2 = lora_A @ R_v   (forward rotations, level j = 0 .. m-1)
//   y_p = c*x_p + s*x_q ; y_q = -s*x_p + c*x_q
// One block per row of A (32 blocks).
// ===========================================================================
__global__ __launch_bounds__(256) void k_rotA(const float* __restrict__ A,
                                              const float* __restrict__ th,
                                              float* __restrict__ A2) {
  __shared__ float buf[4096];
  const int row = blockIdx.x;
  const int t = threadIdx.x;
  const float* src = A + (size_t)row * 4096;
  for (int p = 0; p < 16; ++p) buf[p * 256 + t] = src[p * 256 + t];
  __syncthreads();
  for (int j = 0; j < 12; ++j) {
    const int k = 4096 >> j;
    const int half = k >> 1;
    const int lh = 11 - j;  // log2(half)
    for (int p = 0; p < 8; ++p) {
      int tp = p * 256 + t;                 // pair id 0..2047
      int b = tp >> lh;
      int i = tp & (half - 1);
      int pi = b * k + i;
      int qi = pi + half;
      float s, c;
      sincosf(th[j * 2048 + tp], &s, &c);
      float xp = buf[pi], xq = buf[qi];
      buf[pi] = c * xp + s * xq;
      buf[qi] = -s * xp + c * xq;
    }
    __syncthreads();
  }
  for (int p = 0; p < 16; ++p) A2[(size_t)row * 4096 + p * 256 + t] = buf[p * 256 + t];
}

// ===========================================================================
// Kernel 2: B2 = SCALING * (R_u @ lora_B)  (column rotations, j = m-1 .. 0)
//   y_p = c*x_p - s*x_q ; y_q = s*x_p + c*x_q
// One block per column of B (32 blocks). B layout (4096, 32) row-major.
// ===========================================================================
__global__ __launch_bounds__(256) void k_rotB(const float* __restrict__ B,
                                              const float* __restrict__ th,
                                              float* __restrict__ B2) {
  __shared__ float buf[4096];
  const int col = blockIdx.x;
  const int t = threadIdx.x;
  for (int p = 0; p < 16; ++p) buf[p * 256 + t] = B[(size_t)(p * 256 + t) * 32 + col];
  __syncthreads();
  for (int j = 11; j >= 0; --j) {
    const int k = 4096 >> j;
    const int half = k >> 1;
    const int lh = 11 - j;
    for (int p = 0; p < 8; ++p) {
      int tp = p * 256 + t;
      int b = tp >> lh;
      int i = tp & (half - 1);
      int pi = b * k + i;
      int qi = pi + half;
      float s, c;
      sincosf(th[j * 2048 + tp], &s, &c);
      float xp = buf[pi], xq = buf[qi];
      buf[pi] = c * xp - s * xq;
      buf[qi] = s * xp + c * xq;
    }
    __syncthreads();
  }
  for (int p = 0; p < 16; ++p)
    B2[(size_t)(p * 256 + t) * 32 + col] = SCALING * buf[p * 256 + t];
}

// ===========================================================================
// Kernel 3: W'[n][k] = (codes[n][k]-8)*scales[n][k/64] + sum_r B2[n][r]*A2[r][k]
// bf16 output. Tile: 128 rows x 512 cols per block; A2 slice + B2 slice in LDS.
// ===========================================================================
__global__ __launch_bounds__(256) void k_wprime(const int* __restrict__ codes,
                                                const float* __restrict__ scales,
                                                const float* __restrict__ A2,
                                                const float* __restrict__ B2,
                                                u16* __restrict__ Wq) {
  __shared__ float A2s[32][516];   // padded: row stride 516 (16B-aligned, bank-spread)
  __shared__ float B2s[128][33];
  const int t = threadIdx.x;
  const int n0 = (blockIdx.x >> 3) << 7;  // 32 row tiles of 128
  const int k0 = (blockIdx.x & 7) << 9;   // 8 col tiles of 512

  // stage A2 slice [32][512]
  for (int q = 0; q < 16; ++q) {
    int f = q * 1024 + t * 4;
    int r = f >> 9, c = f & 511;
    f32x4 v = *(const f32x4*)(A2 + (size_t)r * 4096 + k0 + c);
    *(f32x4*)&A2s[r][c] = v;
  }
  // stage B2 slice [128][32]
  for (int q = 0; q < 4; ++q) {
    int f = q * 1024 + t * 4;
    int i = f >> 5, r = f & 31;
    f32x4 v = *(const f32x4*)(B2 + (size_t)(n0 + i) * 32 + r);
    B2s[i][r] = v[0]; B2s[i][r + 1] = v[1]; B2s[i][r + 2] = v[2]; B2s[i][r + 3] = v[3];
  }
  __syncthreads();

  const int tr = t >> 3, tc = t & 7;
#pragma unroll 1
  for (int cc = 0; cc < 8; ++cc) {
    const int kc = cc * 64 + tc * 8;   // col in tile (interleaved -> coalesced LDS)
    const int kg = k0 + kc;
    float acc[4][8];
#pragma unroll
    for (int i = 0; i < 4; ++i) {
      const int n = n0 + tr * 4 + i;
      const float sc = scales[((size_t)n << 6) + (kg >> 6)];
      const i32x4 c0 = *(const i32x4*)(codes + (size_t)n * 4096 + kg);
      const i32x4 c1 = *(const i32x4*)(codes + (size_t)n * 4096 + kg + 4);
#pragma unroll
      for (int e = 0; e < 4; ++e) {
        acc[i][e]     = (float)(c0[e] - 8) * sc;
        acc[i][4 + e] = (float)(c1[e] - 8) * sc;
      }
    }
#pragma unroll
    for (int r = 0; r < 32; ++r) {
      const f32x4 a0 = *(const f32x4*)&A2s[r][kc];
      const f32x4 a1 = *(const f32x4*)&A2s[r][kc + 4];
#pragma unroll
      for (int i = 0; i < 4; ++i) {
        const float bv = B2s[tr * 4 + i][r];
#pragma unroll
        for (int e = 0; e < 4; ++e) {
          acc[i][e]     += bv * a0[e];
          acc[i][4 + e] += bv * a1[e];
        }
      }
    }
#pragma unroll
    for (int i = 0; i < 4; ++i) {
      const int n = n0 + tr * 4 + i;
      s16x8 o;
#pragma unroll
      for (int e = 0; e < 8; ++e) o[e] = (short)f2bf(acc[i][e]);
      *(s16x8*)(Wq + (size_t)n * 4096 + kg) = o;
    }
  }
}

// ===========================================================================
// Kernel 4: x (f32) -> bf16, 8 elements/thread
// ===========================================================================
__global__ __launch_bounds__(256) void k_xbf16(const float* __restrict__ x,
                                               u16* __restrict__ xb) {
  const size_t i = ((size_t)blockIdx.x * 256 + threadIdx.x) * 8;
  f32x4 a = *(const f32x4*)(x + i);
  f32x4 b = *(const f32x4*)(x + i + 4);
  s16x8 o;
  o[0] = (short)f2bf(a[0]); o[1] = (short)f2bf(a[1]);
  o[2] = (short)f2bf(a[2]); o[3] = (short)f2bf(a[3]);
  o[4] = (short)f2bf(b[0]); o[5] = (short)f2bf(b[1]);
  o[6] = (short)f2bf(b[2]); o[7] = (short)f2bf(b[3]);
  *(s16x8*)(xb + i) = o;
}

// ===========================================================================
// Kernel 5: main GEMM  out[m][n] = sum_k xb[m][k]*Wq[n][k] + bias[n]
// 128x128 tile, BK=64, 4 waves (2x2 of 64x64), mfma 16x16x32 bf16.
// global_load_lds w16 staging, double-buffered LDS, XOR swizzle (slot ^= row&7),
// XCD-aware block swizzle.
// ===========================================================================
__device__ __forceinline__ void stage_tile(u16* lds, const u16* gbase, int t) {
#pragma unroll
  for (int c = 0; c < 4; ++c) {
    int flat = (c * 256 + t) * 8;     // element index; LDS dest linear
    int row = flat >> 6;              // 64 elems per row
    int slot = (flat >> 3) & 7;
    int lslot = slot ^ (row & 7);     // inverse-swizzled global source
    gload_lds16(gbase + ((size_t)row << 12) + lslot * 8, lds + flat);
  }
}

__global__ __launch_bounds__(256, 2) void k_gemm(const u16* __restrict__ Abf,
                                                 const u16* __restrict__ Bbf,
                                                 const float* __restrict__ bias,
                                                 float* __restrict__ out) {
  __shared__ __align__(16) u16 As[2][128 * 64];
  __shared__ __align__(16) u16 Bs[2][128 * 64];

  const int bid = blockIdx.x;
  const int wg = (bid & 7) * 256 + (bid >> 3);  // 2048 % 8 == 0: bijective
  const int mt = wg >> 5;    // 64 M-tiles
  const int nt = wg & 31;    // 32 N-tiles
  const int m0 = mt << 7, n0 = nt << 7;
  const int t = threadIdx.x;
  const int lane = t & 63;
  const int wave = t >> 6;
  const int wm = (wave >> 1) << 6;
  const int wn = (wave & 1) << 6;

  const u16* Ab = Abf + ((size_t)m0 << 12);
  const u16* Bb = Bbf + ((size_t)n0 << 12);

  f32x4 acc[4][4] = {};

  stage_tile(As[0], Ab, t);
  stage_tile(Bs[0], Bb, t);

  int cur = 0;
  for (int kt = 0; kt < 64; ++kt) {
    __syncthreads();   // drains vmcnt(0)+lgkmcnt(0): buf[cur] staged, buf[cur^1] free
    if (kt < 63) {
      stage_tile(As[cur ^ 1], Ab + (kt + 1) * 64, t);
      stage_tile(Bs[cur ^ 1], Bb + (kt + 1) * 64, t);
    }
    const u16* as = As[cur];
    const u16* bs = Bs[cur];
#pragma unroll
    for (int kk = 0; kk < 2; ++kk) {
      s16x8 af[4], bfr[4];
#pragma unroll
      for (int i = 0; i < 4; ++i) {
        int row = wm + i * 16 + (lane & 15);
        int slot = kk * 4 + (lane >> 4);
        af[i] = *(const s16x8*)(as + row * 64 + ((slot ^ (row & 7)) << 3));
      }
#pragma unroll
      for (int j = 0; j < 4; ++j) {
        int row = wn + j * 16 + (lane & 15);
        int slot = kk * 4 + (lane >> 4);
        bfr[j] = *(const s16x8*)(bs + row * 64 + ((slot ^ (row & 7)) << 3));
      }
#pragma unroll
      for (int i = 0; i < 4; ++i)
#pragma unroll
        for (int j = 0; j < 4; ++j)
          acc[i][j] = mfma_bf16(af[i], bfr[j], acc[i][j]);
    }
    cur ^= 1;
  }

  // epilogue: C/D layout col = lane&15, row = (lane>>4)*4 + v
  const int col_lane = lane & 15;
  const int rgrp = lane >> 4;
  float bj[4];
#pragma unroll
  for (int j = 0; j < 4; ++j) bj[j] = bias[n0 + wn + j * 16 + col_lane];
#pragma unroll
  for (int i = 0; i < 4; ++i) {
    const int row0 = m0 + wm + i * 16 + rgrp * 4;
#pragma unroll
    for (int j = 0; j < 4; ++j) {
      const int col = n0 + wn + j * 16 + col_lane;
#pragma unroll
      for (int v = 0; v < 4; ++v)
        out[(size_t)(row0 + v) * 4096 + col] = acc[i][j][v] + bj[j];
    }
  }
}

// ===========================================================================
extern "C" void kernel_launch(void* const* d_in, const int* in_sizes, int n_in,
                              void* d_out, int out_size, void* d_ws, size_t ws_size,
                              hipStream_t stream) {
  const float* x      = (const float*)d_in[0];
  const int*   codes  = (const int*)d_in[1];
  const float* scales = (const float*)d_in[2];
  const float* th_v   = (const float*)d_in[3];
  const float* th_u   = (const float*)d_in[4];
  const float* lA     = (const float*)d_in[5];
  const float* lB     = (const float*)d_in[6];
  const float* bias   = (const float*)d_in[7];
  float* out = (float*)d_out;

  char* ws = (char*)d_ws;
  float* A2 = (float*)ws;                              // 512 KB
  float* B2 = (float*)(ws + (512u << 10));             // 512 KB
  u16*   Wq = (u16*)(ws + (1u << 20));                 // 32 MB
  u16*   xb = (u16*)(ws + (1u << 20) + (32u << 20));   // 64 MB

  k_rotA<<<32, 256, 0, stream>>>(lA, th_v, A2);
  k_rotB<<<32, 256, 0, stream>>>(lB, th_u, B2);
  k_wprime<<<256, 256, 0, stream>>>(codes, scales, A2, B2, Wq);
  k_xbf16<<<16384, 256, 0, stream>>>(x, xb);
  k_gemm<<<2048, 256, 0, stream>>>(xb, Wq, bias, out);
}

// Round 3
// 433.459 us; speedup vs baseline: 1.1740x; 1.1740x over previous
//
#include <hip/hip_runtime.h>
#include <cstdint>
#include <type_traits>
#include <utility>

// ---------------------------------------------------------------------------
// SOARALinearLayer: out = x @ (W_deq + B2@A2)^T + bias
//   A2 = lora_A @ R_v, B2 = R_u @ lora_B (butterflies folded into LoRA factors)
// => one bf16 MFMA GEMM (M=8192, N=4096, K=4096) + tiny prep.
// R3: GEMM moved from 128^2 2-phase (670 TF measured) to the 256^2 8-phase
// template (T1+T2+T3+T4+T5): counted vmcnt(4), 2 K-tiles/iter, 16 MFMA/phase.
// ---------------------------------------------------------------------------

typedef unsigned short u16;
typedef unsigned int   u32;
typedef short  s16x8 __attribute__((ext_vector_type(8)));
typedef __bf16 b16x8 __attribute__((ext_vector_type(8)));
typedef float  f32x4 __attribute__((ext_vector_type(4)));
typedef int    i32x4 __attribute__((ext_vector_type(4)));

#define SCALING 1.0f   /* ALPHA/RANK = 32/32 */

__device__ __forceinline__ u16 f2bf(float f) {
  u32 u = __builtin_bit_cast(u32, f);
  u += 0x7FFFu + ((u >> 16) & 1u);
  return (u16)(u >> 16);
}

template <typename T, typename = void>
struct mfma_takes_i16 : std::false_type {};
template <typename T>
struct mfma_takes_i16<T, std::void_t<decltype(__builtin_amdgcn_mfma_f32_16x16x32_bf16(
    std::declval<T>(), std::declval<T>(), std::declval<f32x4>(), 0, 0, 0))>>
    : std::true_type {};

template <typename T>
__device__ __forceinline__ f32x4 mfma_bf16(T a, T b, f32x4 c) {
  if constexpr (mfma_takes_i16<T>::value) {
    return __builtin_amdgcn_mfma_f32_16x16x32_bf16(a, b, c, 0, 0, 0);
  } else {
    return __builtin_amdgcn_mfma_f32_16x16x32_bf16(
        __builtin_bit_cast(b16x8, a), __builtin_bit_cast(b16x8, b), c, 0, 0, 0);
  }
}

__device__ __forceinline__ void gload_lds16(const void* g, void* l) {
  __builtin_amdgcn_global_load_lds((const __attribute__((address_space(1))) u32*)g,
                                   (__attribute__((address_space(3))) u32*)l,
                                   16, 0, 0);
}

// ===========================================================================
// Prep kernels (unchanged from verified R2 kernel)
// ===========================================================================
__global__ __launch_bounds__(256) void k_rotA(const float* __restrict__ A,
                                              const float* __restrict__ th,
                                              float* __restrict__ A2) {
  __shared__ float buf[4096];
  const int row = blockIdx.x;
  const int t = threadIdx.x;
  const float* src = A + (size_t)row * 4096;
  for (int p = 0; p < 16; ++p) buf[p * 256 + t] = src[p * 256 + t];
  __syncthreads();
  for (int j = 0; j < 12; ++j) {
    const int k = 4096 >> j;
    const int half = k >> 1;
    const int lh = 11 - j;
    for (int p = 0; p < 8; ++p) {
      int tp = p * 256 + t;
      int b = tp >> lh;
      int i = tp & (half - 1);
      int pi = b * k + i;
      int qi = pi + half;
      float s, c;
      sincosf(th[j * 2048 + tp], &s, &c);
      float xp = buf[pi], xq = buf[qi];
      buf[pi] = c * xp + s * xq;
      buf[qi] = -s * xp + c * xq;
    }
    __syncthreads();
  }
  for (int p = 0; p < 16; ++p) A2[(size_t)row * 4096 + p * 256 + t] = buf[p * 256 + t];
}

__global__ __launch_bounds__(256) void k_rotB(const float* __restrict__ B,
                                              const float* __restrict__ th,
                                              float* __restrict__ B2) {
  __shared__ float buf[4096];
  const int col = blockIdx.x;
  const int t = threadIdx.x;
  for (int p = 0; p < 16; ++p) buf[p * 256 + t] = B[(size_t)(p * 256 + t) * 32 + col];
  __syncthreads();
  for (int j = 11; j >= 0; --j) {
    const int k = 4096 >> j;
    const int half = k >> 1;
    const int lh = 11 - j;
    for (int p = 0; p < 8; ++p) {
      int tp = p * 256 + t;
      int b = tp >> lh;
      int i = tp & (half - 1);
      int pi = b * k + i;
      int qi = pi + half;
      float s, c;
      sincosf(th[j * 2048 + tp], &s, &c);
      float xp = buf[pi], xq = buf[qi];
      buf[pi] = c * xp - s * xq;
      buf[qi] = s * xp + c * xq;
    }
    __syncthreads();
  }
  for (int p = 0; p < 16; ++p)
    B2[(size_t)(p * 256 + t) * 32 + col] = SCALING * buf[p * 256 + t];
}

__global__ __launch_bounds__(256) void k_wprime(const int* __restrict__ codes,
                                                const float* __restrict__ scales,
                                                const float* __restrict__ A2,
                                                const float* __restrict__ B2,
                                                u16* __restrict__ Wq) {
  __shared__ float A2s[32][516];
  __shared__ float B2s[128][33];
  const int t = threadIdx.x;
  const int n0 = (blockIdx.x >> 3) << 7;
  const int k0 = (blockIdx.x & 7) << 9;

  for (int q = 0; q < 16; ++q) {
    int f = q * 1024 + t * 4;
    int r = f >> 9, c = f & 511;
    f32x4 v = *(const f32x4*)(A2 + (size_t)r * 4096 + k0 + c);
    *(f32x4*)&A2s[r][c] = v;
  }
  for (int q = 0; q < 4; ++q) {
    int f = q * 1024 + t * 4;
    int i = f >> 5, r = f & 31;
    f32x4 v = *(const f32x4*)(B2 + (size_t)(n0 + i) * 32 + r);
    B2s[i][r] = v[0]; B2s[i][r + 1] = v[1]; B2s[i][r + 2] = v[2]; B2s[i][r + 3] = v[3];
  }
  __syncthreads();

  const int tr = t >> 3, tc = t & 7;
#pragma unroll 1
  for (int cc = 0; cc < 8; ++cc) {
    const int kc = cc * 64 + tc * 8;
    const int kg = k0 + kc;
    float acc[4][8];
#pragma unroll
    for (int i = 0; i < 4; ++i) {
      const int n = n0 + tr * 4 + i;
      const float sc = scales[((size_t)n << 6) + (kg >> 6)];
      const i32x4 c0 = *(const i32x4*)(codes + (size_t)n * 4096 + kg);
      const i32x4 c1 = *(const i32x4*)(codes + (size_t)n * 4096 + kg + 4);
#pragma unroll
      for (int e = 0; e < 4; ++e) {
        acc[i][e]     = (float)(c0[e] - 8) * sc;
        acc[i][4 + e] = (float)(c1[e] - 8) * sc;
      }
    }
#pragma unroll
    for (int r = 0; r < 32; ++r) {
      const f32x4 a0 = *(const f32x4*)&A2s[r][kc];
      const f32x4 a1 = *(const f32x4*)&A2s[r][kc + 4];
#pragma unroll
      for (int i = 0; i < 4; ++i) {
        const float bv = B2s[tr * 4 + i][r];
#pragma unroll
        for (int e = 0; e < 4; ++e) {
          acc[i][e]     += bv * a0[e];
          acc[i][4 + e] += bv * a1[e];
        }
      }
    }
#pragma unroll
    for (int i = 0; i < 4; ++i) {
      const int n = n0 + tr * 4 + i;
      s16x8 o;
#pragma unroll
      for (int e = 0; e < 8; ++e) o[e] = (short)f2bf(acc[i][e]);
      *(s16x8*)(Wq + (size_t)n * 4096 + kg) = o;
    }
  }
}

__global__ __launch_bounds__(256) void k_xbf16(const float* __restrict__ x,
                                               u16* __restrict__ xb) {
  const size_t i = ((size_t)blockIdx.x * 256 + threadIdx.x) * 8;
  f32x4 a = *(const f32x4*)(x + i);
  f32x4 b = *(const f32x4*)(x + i + 4);
  s16x8 o;
  o[0] = (short)f2bf(a[0]); o[1] = (short)f2bf(a[1]);
  o[2] = (short)f2bf(a[2]); o[3] = (short)f2bf(a[3]);
  o[4] = (short)f2bf(b[0]); o[5] = (short)f2bf(b[1]);
  o[6] = (short)f2bf(b[2]); o[7] = (short)f2bf(b[3]);
  *(s16x8*)(xb + i) = o;
}

// ===========================================================================
// Main GEMM, 256x256 tile, BK=64, 8-phase counted-vmcnt schedule.
// 512 thr = 8 waves (2M x 4N), per-wave out 128x64, acc = 8x4 f32x4 frags.
// Per K-tile (4 phases): quadrants (qm,qn) in zigzag (0,0)(0,1)(1,1)(1,0).
// LDS regions per buffer: A0(rows 0-127) A1(128-255) B0(cols 0-127) B1.
// Stage order (steady, iter it computes K=2it [buf0] then 2it+1 [buf1]):
//   p1->K(2it+1).A1  p2->K(2it+1).B0  p3->K(2it+2).A0  p4->K(2it+2).B1
//   p5->K(2it+2).A1  p6->K(2it+2).B0  p7->K(2it+3).A0  p8->K(2it+3).B1
// Every staged region is written strictly after its last ds_read (barrier
// between); vmcnt(4) at p4/p8 guarantees all-but-last-2 half-tiles landed.
// ===========================================================================
#define LGKM0()  do { asm volatile("s_waitcnt lgkmcnt(0)" ::: "memory"); \
                      __builtin_amdgcn_sched_barrier(0); } while (0)
#define LGKM8()  do { asm volatile("s_waitcnt lgkmcnt(8)" ::: "memory"); } while (0)
#define VMC4()   do { asm volatile("s_waitcnt vmcnt(4)" ::: "memory"); \
                      __builtin_amdgcn_sched_barrier(0); } while (0)
#define BAR()    __builtin_amdgcn_s_barrier()

template <int QM>
__device__ __forceinline__ void load_a(s16x8 a[4][2], const u16* as, int wm, int lane) {
  const int rl = lane & 15, sl = lane >> 4;
#pragma unroll
  for (int i = 0; i < 4; ++i) {
    const int row = QM * 128 + wm + i * 16 + rl;
#pragma unroll
    for (int kk = 0; kk < 2; ++kk) {
      const int slot = kk * 4 + sl;
      a[i][kk] = *(const s16x8*)(as + row * 64 + ((slot ^ (row & 7)) << 3));
    }
  }
}

template <int QN>
__device__ __forceinline__ void load_b(s16x8 b[2][2], const u16* bs, int wn, int lane) {
  const int rl = lane & 15, sl = lane >> 4;
#pragma unroll
  for (int j = 0; j < 2; ++j) {
    const int row = QN * 128 + wn + j * 16 + rl;
#pragma unroll
    for (int kk = 0; kk < 2; ++kk) {
      const int slot = kk * 4 + sl;
      b[j][kk] = *(const s16x8*)(bs + row * 64 + ((slot ^ (row & 7)) << 3));
    }
  }
}

template <int QM, int QN>
__device__ __forceinline__ void mma16(f32x4 acc[8][4], s16x8 a[4][2], s16x8 b[2][2]) {
  __builtin_amdgcn_s_setprio(1);
#pragma unroll
  for (int kk = 0; kk < 2; ++kk)
#pragma unroll
    for (int i = 0; i < 4; ++i)
#pragma unroll
      for (int j = 0; j < 2; ++j)
        acc[QM * 4 + i][QN * 2 + j] = mfma_bf16(a[i][kk], b[j][kk], acc[QM * 4 + i][QN * 2 + j]);
  __builtin_amdgcn_s_setprio(0);
}

__global__ __launch_bounds__(512, 2) void k_gemm8(const u16* __restrict__ Abf,
                                                  const u16* __restrict__ Bbf,
                                                  const float* __restrict__ bias,
                                                  float* __restrict__ out) {
  __shared__ __align__(16) u16 As[2][256 * 64];
  __shared__ __align__(16) u16 Bs[2][256 * 64];

  const int bid = blockIdx.x;
  const int wg = (bid & 7) * 64 + (bid >> 3);   // 512 % 8 == 0: bijective XCD swizzle
  const int mt = wg >> 4, nt = wg & 15;
  const int m0 = mt << 8, n0 = nt << 8;
  const int tid = threadIdx.x;
  const int lane = tid & 63;
  const int wid = tid >> 6;
  const int wm = (wid >> 2) * 64;   // row sub-offset within each 128-row half
  const int wn = (wid & 3) * 32;    // col sub-offset within each 128-col half

  // staging per-thread geometry: 2 x 16B per half-tile (128 rows x 64 cols)
  int rowc[2], swzc[2];
#pragma unroll
  for (int c = 0; c < 2; ++c) {
    const int flat = (c * 512 + tid) * 8;
    rowc[c] = flat >> 6;
    const int slot = (flat >> 3) & 7;
    swzc[c] = (slot ^ (rowc[c] & 7)) << 3;   // inverse-swizzled global source
  }
  const u16* Ap0 = Abf + ((size_t)m0) * 4096;
  const u16* Ap1 = Abf + ((size_t)(m0 + 128)) * 4096;
  const u16* Bp0 = Bbf + ((size_t)n0) * 4096;
  const u16* Bp1 = Bbf + ((size_t)(n0 + 128)) * 4096;

#define STAGE(gpan, kt, ldsbase)                                              \
  do {                                                                        \
    _Pragma("unroll")                                                         \
    for (int c = 0; c < 2; ++c)                                               \
      gload_lds16((gpan) + (size_t)rowc[c] * 4096 + (kt) * 64 + swzc[c],      \
                  (ldsbase) + (c * 512 + tid) * 8);                           \
  } while (0)

  f32x4 acc[8][4] = {};
  s16x8 a[4][2], b[2][2];

  // ---- prologue: K0 full -> buf0; K1.A0, K1.B1 -> buf1 ----
  STAGE(Ap0, 0, As[0]);
  STAGE(Ap1, 0, As[0] + 8192);
  STAGE(Bp0, 0, Bs[0]);
  STAGE(Bp1, 0, Bs[0] + 8192);
  STAGE(Ap0, 1, As[1]);
  STAGE(Bp1, 1, Bs[1] + 8192);
  VMC4();          // K0 landed; K1.A0/B1 still in flight
  BAR();

#pragma unroll 1
  for (int it = 0; it < 32; ++it) {
    const int kn1 = 2 * it + 1;
    const int ktA = (2 * it + 2 < 64) ? 2 * it + 2 : 63;  // clamped tail (dead regions)
    const int ktB = (2 * it + 3 < 64) ? 2 * it + 3 : 63;

    // ---- p1: compute buf0 (0,0); stage K(2it+1).A1 -> buf1.A1 ----
    load_a<0>(a, As[0], wm, lane);
    load_b<0>(b, Bs[0], wn, lane);
    STAGE(Ap1, kn1, As[1] + 8192);
    LGKM8();
    BAR(); LGKM0();
    mma16<0, 0>(acc, a, b);
    BAR();
    // ---- p2: (0,1); stage K(2it+1).B0 -> buf1.B0 ----
    load_b<1>(b, Bs[0], wn, lane);
    STAGE(Bp0, kn1, Bs[1]);
    BAR(); LGKM0();
    mma16<0, 1>(acc, a, b);
    BAR();
    // ---- p3: (1,1); stage K(2it+2).A0 -> buf0.A0 ----
    load_a<1>(a, As[0], wm, lane);
    STAGE(Ap0, ktA, As[0]);
    BAR(); LGKM0();
    mma16<1, 1>(acc, a, b);
    BAR();
    // ---- p4: (1,0); stage K(2it+2).B1 -> buf0.B1; vmcnt ----
    load_b<0>(b, Bs[0], wn, lane);
    STAGE(Bp1, ktA, Bs[0] + 8192);
    BAR(); LGKM0();
    mma16<1, 0>(acc, a, b);
    VMC4();
    BAR();
    // ---- p5: compute buf1 (0,0); stage K(2it+2).A1 -> buf0.A1 ----
    load_a<0>(a, As[1], wm, lane);
    load_b<0>(b, Bs[1], wn, lane);
    STAGE(Ap1, ktA, As[0] + 8192);
    LGKM8();
    BAR(); LGKM0();
    mma16<0, 0>(acc, a, b);
    BAR();
    // ---- p6: (0,1); stage K(2it+2).B0 -> buf0.B0 ----
    load_b<1>(b, Bs[1], wn, lane);
    STAGE(Bp0, ktA, Bs[0]);
    BAR(); LGKM0();
    mma16<0, 1>(acc, a, b);
    BAR();
    // ---- p7: (1,1); stage K(2it+3).A0 -> buf1.A0 ----
    load_a<1>(a, As[1], wm, lane);
    STAGE(Ap0, ktB, As[1]);
    BAR(); LGKM0();
    mma16<1, 1>(acc, a, b);
    BAR();
    // ---- p8: (1,0); stage K(2it+3).B1 -> buf1.B1; vmcnt ----
    load_b<0>(b, Bs[1], wn, lane);
    STAGE(Bp1, ktB, Bs[1] + 8192);
    BAR(); LGKM0();
    mma16<1, 0>(acc, a, b);
    VMC4();
    BAR();
  }

  // ---- epilogue: C/D layout col = lane&15, row = (lane>>4)*4 + v ----
  const int rl = lane & 15, rg = lane >> 4;
  float bv[4];
#pragma unroll
  for (int j = 0; j < 4; ++j)
    bv[j] = bias[n0 + (j >> 1) * 128 + wn + (j & 1) * 16 + rl];
#pragma unroll
  for (int i = 0; i < 8; ++i) {
    const int row0 = m0 + (i >> 2) * 128 + wm + (i & 3) * 16 + rg * 4;
#pragma unroll
    for (int j = 0; j < 4; ++j) {
      const int col = n0 + (j >> 1) * 128 + wn + (j & 1) * 16 + rl;
#pragma unroll
      for (int v = 0; v < 4; ++v)
        out[(size_t)(row0 + v) * 4096 + col] = acc[i][j][v] + bv[j];
    }
  }
#undef STAGE
}

// ===========================================================================
extern "C" void kernel_launch(void* const* d_in, const int* in_sizes, int n_in,
                              void* d_out, int out_size, void* d_ws, size_t ws_size,
                              hipStream_t stream) {
  const float* x      = (const float*)d_in[0];
  const int*   codes  = (const int*)d_in[1];
  const float* scales = (const float*)d_in[2];
  const float* th_v   = (const float*)d_in[3];
  const float* th_u   = (const float*)d_in[4];
  const float* lA     = (const float*)d_in[5];
  const float* lB     = (const float*)d_in[6];
  const float* bias   = (const float*)d_in[7];
  float* out = (float*)d_out;

  char* ws = (char*)d_ws;
  float* A2 = (float*)ws;                              // 512 KB
  float* B2 = (float*)(ws + (512u << 10));             // 512 KB
  u16*   Wq = (u16*)(ws + (1u << 20));                 // 32 MB
  u16*   xb = (u16*)(ws + (1u << 20) + (32u << 20));   // 64 MB

  k_rotA<<<32, 256, 0, stream>>>(lA, th_v, A2);
  k_rotB<<<32, 256, 0, stream>>>(lB, th_u, B2);
  k_wprime<<<256, 256, 0, stream>>>(codes, scales, A2, B2, Wq);
  k_xbf16<<<16384, 256, 0, stream>>>(x, xb);
  k_gemm8<<<512, 512, 0, stream>>>(xb, Wq, bias, out);
}

// Round 4
// 372.846 us; speedup vs baseline: 1.3649x; 1.1626x over previous
//
#include <hip/hip_runtime.h>
#include <cstdint>
#include <type_traits>
#include <utility>

// ---------------------------------------------------------------------------
// SOARALinearLayer: out = x @ (W_deq + B2@A2)^T + bias
//   A2 = lora_A @ R_v, B2 = R_u @ lora_B (butterflies folded into LoRA factors)
// => one bf16 MFMA GEMM (M=8192, N=4096, K=4096) + tiny prep.
// R4: remove forced lgkmcnt(0) drains from the 8-phase GEMM (plain-C++ ds_reads
// get compiler fine-grained waits; consumption-before-barrier keeps the
// staging race-free). Prep: wprime 256->1024 blocks; rotA+rotB merged.
// ---------------------------------------------------------------------------

typedef unsigned short u16;
typedef unsigned int   u32;
typedef short  s16x8 __attribute__((ext_vector_type(8)));
typedef __bf16 b16x8 __attribute__((ext_vector_type(8)));
typedef float  f32x4 __attribute__((ext_vector_type(4)));
typedef int    i32x4 __attribute__((ext_vector_type(4)));

#define SCALING 1.0f   /* ALPHA/RANK = 32/32 */

__device__ __forceinline__ u16 f2bf(float f) {
  u32 u = __builtin_bit_cast(u32, f);
  u += 0x7FFFu + ((u >> 16) & 1u);
  return (u16)(u >> 16);
}

template <typename T, typename = void>
struct mfma_takes_i16 : std::false_type {};
template <typename T>
struct mfma_takes_i16<T, std::void_t<decltype(__builtin_amdgcn_mfma_f32_16x16x32_bf16(
    std::declval<T>(), std::declval<T>(), std::declval<f32x4>(), 0, 0, 0))>>
    : std::true_type {};

template <typename T>
__device__ __forceinline__ f32x4 mfma_bf16(T a, T b, f32x4 c) {
  if constexpr (mfma_takes_i16<T>::value) {
    return __builtin_amdgcn_mfma_f32_16x16x32_bf16(a, b, c, 0, 0, 0);
  } else {
    return __builtin_amdgcn_mfma_f32_16x16x32_bf16(
        __builtin_bit_cast(b16x8, a), __builtin_bit_cast(b16x8, b), c, 0, 0, 0);
  }
}

__device__ __forceinline__ void gload_lds16(const void* g, void* l) {
  __builtin_amdgcn_global_load_lds((const __attribute__((address_space(1))) u32*)g,
                                   (__attribute__((address_space(3))) u32*)l,
                                   16, 0, 0);
}

// ===========================================================================
// Kernel 1 (merged): blocks 0-31: A2 = lora_A @ R_v ; blocks 32-63: B2 = R_u@B
// ===========================================================================
__global__ __launch_bounds__(256) void k_rot(const float* __restrict__ A,
                                             const float* __restrict__ thA,
                                             const float* __restrict__ B,
                                             const float* __restrict__ thB,
                                             float* __restrict__ A2,
                                             float* __restrict__ B2) {
  __shared__ float buf[4096];
  const int t = threadIdx.x;
  if (blockIdx.x < 32) {
    const int row = blockIdx.x;
    const float* src = A + (size_t)row * 4096;
    for (int p = 0; p < 16; ++p) buf[p * 256 + t] = src[p * 256 + t];
    __syncthreads();
    for (int j = 0; j < 12; ++j) {
      const int k = 4096 >> j;
      const int half = k >> 1;
      const int lh = 11 - j;
      for (int p = 0; p < 8; ++p) {
        int tp = p * 256 + t;
        int b = tp >> lh;
        int i = tp & (half - 1);
        int pi = b * k + i;
        int qi = pi + half;
        float s, c;
        sincosf(thA[j * 2048 + tp], &s, &c);
        float xp = buf[pi], xq = buf[qi];
        buf[pi] = c * xp + s * xq;
        buf[qi] = -s * xp + c * xq;
      }
      __syncthreads();
    }
    for (int p = 0; p < 16; ++p) A2[(size_t)row * 4096 + p * 256 + t] = buf[p * 256 + t];
  } else {
    const int col = blockIdx.x - 32;
    for (int p = 0; p < 16; ++p) buf[p * 256 + t] = B[(size_t)(p * 256 + t) * 32 + col];
    __syncthreads();
    for (int j = 11; j >= 0; --j) {
      const int k = 4096 >> j;
      const int half = k >> 1;
      const int lh = 11 - j;
      for (int p = 0; p < 8; ++p) {
        int tp = p * 256 + t;
        int b = tp >> lh;
        int i = tp & (half - 1);
        int pi = b * k + i;
        int qi = pi + half;
        float s, c;
        sincosf(thB[j * 2048 + tp], &s, &c);
        float xp = buf[pi], xq = buf[qi];
        buf[pi] = c * xp - s * xq;
        buf[qi] = s * xp + c * xq;
      }
      __syncthreads();
    }
    for (int p = 0; p < 16; ++p)
      B2[(size_t)(p * 256 + t) * 32 + col] = SCALING * buf[p * 256 + t];
  }
}

// ===========================================================================
// Kernel 2: W'[n][k] = (codes-8)*scale + sum_r B2[n][r]*A2[r][k], bf16 out.
// 1024 blocks: 32 n-tiles x 32 k-tiles of 128x128. B2 transposed in LDS.
// ===========================================================================
__global__ __launch_bounds__(256) void k_wprime(const int* __restrict__ codes,
                                                const float* __restrict__ scales,
                                                const float* __restrict__ A2,
                                                const float* __restrict__ B2,
                                                u16* __restrict__ Wq) {
  __shared__ float A2s[32][128];
  __shared__ float B2t[32][128];
  const int t = threadIdx.x;
  const int n0 = (blockIdx.x >> 5) << 7;
  const int k0 = (blockIdx.x & 31) << 7;

  // stage A2 slice [32][128]
#pragma unroll
  for (int q = 0; q < 4; ++q) {
    int f = (q * 256 + t) * 4;
    int r = f >> 7, c = f & 127;
    *(f32x4*)&A2s[r][c] = *(const f32x4*)(A2 + (size_t)r * 4096 + k0 + c);
  }
  // stage B2 slice transposed: B2t[r][i] = B2[n0+i][r]
#pragma unroll
  for (int q = 0; q < 4; ++q) {
    int f = (q * 256 + t) * 4;
    int i = f >> 5, r = f & 31;
    f32x4 v = *(const f32x4*)(B2 + (size_t)(n0 + i) * 32 + r);
    B2t[r][i] = v[0]; B2t[r + 1][i] = v[1]; B2t[r + 2][i] = v[2]; B2t[r + 3][i] = v[3];
  }
  __syncthreads();

  const int tr = t >> 4, tc = t & 15;   // 16 x 16 threads; 8 rows x 8 cols each
  const int kg = k0 + tc * 8;
  float acc[8][8];
#pragma unroll
  for (int i = 0; i < 8; ++i) {
    const int n = n0 + tr * 8 + i;
    const float sc = scales[((size_t)n << 6) + (kg >> 6)];
    const i32x4 c0 = *(const i32x4*)(codes + (size_t)n * 4096 + kg);
    const i32x4 c1 = *(const i32x4*)(codes + (size_t)n * 4096 + kg + 4);
#pragma unroll
    for (int e = 0; e < 4; ++e) {
      acc[i][e]     = (float)(c0[e] - 8) * sc;
      acc[i][4 + e] = (float)(c1[e] - 8) * sc;
    }
  }
#pragma unroll
  for (int r = 0; r < 32; ++r) {
    const f32x4 a0 = *(const f32x4*)&A2s[r][tc * 8];
    const f32x4 a1 = *(const f32x4*)&A2s[r][tc * 8 + 4];
    const f32x4 b0 = *(const f32x4*)&B2t[r][tr * 8];
    const f32x4 b1 = *(const f32x4*)&B2t[r][tr * 8 + 4];
#pragma unroll
    for (int i = 0; i < 4; ++i) {
#pragma unroll
      for (int e = 0; e < 4; ++e) {
        acc[i][e]         += b0[i] * a0[e];
        acc[i][4 + e]     += b0[i] * a1[e];
        acc[4 + i][e]     += b1[i] * a0[e];
        acc[4 + i][4 + e] += b1[i] * a1[e];
      }
    }
  }
#pragma unroll
  for (int i = 0; i < 8; ++i) {
    const int n = n0 + tr * 8 + i;
    s16x8 o;
#pragma unroll
    for (int e = 0; e < 8; ++e) o[e] = (short)f2bf(acc[i][e]);
    *(s16x8*)(Wq + (size_t)n * 4096 + kg) = o;
  }
}

// ===========================================================================
// Kernel 3: x (f32) -> bf16
// ===========================================================================
__global__ __launch_bounds__(256) void k_xbf16(const float* __restrict__ x,
                                               u16* __restrict__ xb) {
  const size_t i = ((size_t)blockIdx.x * 256 + threadIdx.x) * 8;
  f32x4 a = *(const f32x4*)(x + i);
  f32x4 b = *(const f32x4*)(x + i + 4);
  s16x8 o;
  o[0] = (short)f2bf(a[0]); o[1] = (short)f2bf(a[1]);
  o[2] = (short)f2bf(a[2]); o[3] = (short)f2bf(a[3]);
  o[4] = (short)f2bf(b[0]); o[5] = (short)f2bf(b[1]);
  o[6] = (short)f2bf(b[2]); o[7] = (short)f2bf(b[3]);
  *(s16x8*)(xb + i) = o;
}

// ===========================================================================
// Main GEMM, 256x256 tile, BK=64, 8-phase counted-vmcnt schedule.
// Same verified stage/read schedule as R3; hard lgkmcnt drains removed —
// every ds_read is consumed by an MFMA in its own phase, so compiler-inserted
// fine-grained lgkmcnt enforces completion before the phase-end barrier.
// ===========================================================================
#define CFENCE() asm volatile("" ::: "memory")
#define BAR()    do { CFENCE(); __builtin_amdgcn_s_barrier(); CFENCE(); } while (0)
#define VMC4()   do { asm volatile("s_waitcnt vmcnt(4)" ::: "memory"); \
                      __builtin_amdgcn_sched_barrier(0); } while (0)

template <int QM>
__device__ __forceinline__ void load_a(s16x8 a[4][2], const u16* as, int wm, int lane) {
  const int rl = lane & 15, sl = lane >> 4;
#pragma unroll
  for (int i = 0; i < 4; ++i) {
    const int row = QM * 128 + wm + i * 16 + rl;
#pragma unroll
    for (int kk = 0; kk < 2; ++kk) {
      const int slot = kk * 4 + sl;
      a[i][kk] = *(const s16x8*)(as + row * 64 + ((slot ^ (row & 7)) << 3));
    }
  }
}

template <int QN>
__device__ __forceinline__ void load_b(s16x8 b[2][2], const u16* bs, int wn, int lane) {
  const int rl = lane & 15, sl = lane >> 4;
#pragma unroll
  for (int j = 0; j < 2; ++j) {
    const int row = QN * 128 + wn + j * 16 + rl;
#pragma unroll
    for (int kk = 0; kk < 2; ++kk) {
      const int slot = kk * 4 + sl;
      b[j][kk] = *(const s16x8*)(bs + row * 64 + ((slot ^ (row & 7)) << 3));
    }
  }
}

template <int QM, int QN>
__device__ __forceinline__ void mma16(f32x4 acc[8][4], s16x8 a[4][2], s16x8 b[2][2]) {
  __builtin_amdgcn_s_setprio(1);
#pragma unroll
  for (int kk = 0; kk < 2; ++kk)
#pragma unroll
    for (int i = 0; i < 4; ++i)
#pragma unroll
      for (int j = 0; j < 2; ++j)
        acc[QM * 4 + i][QN * 2 + j] = mfma_bf16(a[i][kk], b[j][kk], acc[QM * 4 + i][QN * 2 + j]);
  __builtin_amdgcn_s_setprio(0);
}

__global__ __launch_bounds__(512, 2) void k_gemm8(const u16* __restrict__ Abf,
                                                  const u16* __restrict__ Bbf,
                                                  const float* __restrict__ bias,
                                                  float* __restrict__ out) {
  __shared__ __align__(16) u16 As[2][256 * 64];
  __shared__ __align__(16) u16 Bs[2][256 * 64];

  const int bid = blockIdx.x;
  const int wg = (bid & 7) * 64 + (bid >> 3);   // 512 % 8 == 0: bijective XCD swizzle
  const int mt = wg >> 4, nt = wg & 15;
  const int m0 = mt << 8, n0 = nt << 8;
  const int tid = threadIdx.x;
  const int lane = tid & 63;
  const int wid = tid >> 6;
  const int wm = (wid >> 2) * 64;   // row sub-offset within each 128-row half
  const int wn = (wid & 3) * 32;    // col sub-offset within each 128-col half

  int rowc[2], swzc[2];
#pragma unroll
  for (int c = 0; c < 2; ++c) {
    const int flat = (c * 512 + tid) * 8;
    rowc[c] = flat >> 6;
    const int slot = (flat >> 3) & 7;
    swzc[c] = (slot ^ (rowc[c] & 7)) << 3;   // inverse-swizzled global source
  }
  const u16* Ap0 = Abf + ((size_t)m0) * 4096;
  const u16* Ap1 = Abf + ((size_t)(m0 + 128)) * 4096;
  const u16* Bp0 = Bbf + ((size_t)n0) * 4096;
  const u16* Bp1 = Bbf + ((size_t)(n0 + 128)) * 4096;

#define STAGE(gpan, kt, ldsbase)                                              \
  do {                                                                        \
    _Pragma("unroll")                                                         \
    for (int c = 0; c < 2; ++c)                                               \
      gload_lds16((gpan) + (size_t)rowc[c] * 4096 + (kt) * 64 + swzc[c],      \
                  (ldsbase) + (c * 512 + tid) * 8);                           \
  } while (0)

  f32x4 acc[8][4] = {};
  s16x8 a[4][2], b[2][2];

  // ---- prologue: K0 full -> buf0; K1.A0, K1.B1 -> buf1 ----
  STAGE(Ap0, 0, As[0]);
  STAGE(Ap1, 0, As[0] + 8192);
  STAGE(Bp0, 0, Bs[0]);
  STAGE(Bp1, 0, Bs[0] + 8192);
  STAGE(Ap0, 1, As[1]);
  STAGE(Bp1, 1, Bs[1] + 8192);
  VMC4();          // K0 landed; K1.A0/B1 still in flight
  BAR();

#pragma unroll 1
  for (int it = 0; it < 32; ++it) {
    const int kn1 = 2 * it + 1;
    const int ktA = (2 * it + 2 < 64) ? 2 * it + 2 : 63;  // clamped tail (dead regions)
    const int ktB = (2 * it + 3 < 64) ? 2 * it + 3 : 63;

    // ---- p1: compute buf0 (0,0); stage K(2it+1).A1 -> buf1.A1 ----
    load_a<0>(a, As[0], wm, lane);
    load_b<0>(b, Bs[0], wn, lane);
    STAGE(Ap1, kn1, As[1] + 8192);
    BAR();
    mma16<0, 0>(acc, a, b);
    BAR();
    // ---- p2: (0,1); stage K(2it+1).B0 -> buf1.B0 ----
    load_b<1>(b, Bs[0], wn, lane);
    STAGE(Bp0, kn1, Bs[1]);
    BAR();
    mma16<0, 1>(acc, a, b);
    BAR();
    // ---- p3: (1,1); stage K(2it+2).A0 -> buf0.A0 ----
    load_a<1>(a, As[0], wm, lane);
    STAGE(Ap0, ktA, As[0]);
    BAR();
    mma16<1, 1>(acc, a, b);
    BAR();
    // ---- p4: (1,0); stage K(2it+2).B1 -> buf0.B1; counted vmcnt ----
    load_b<0>(b, Bs[0], wn, lane);
    STAGE(Bp1, ktA, Bs[0] + 8192);
    BAR();
    mma16<1, 0>(acc, a, b);
    VMC4();
    BAR();
    // ---- p5: compute buf1 (0,0); stage K(2it+2).A1 -> buf0.A1 ----
    load_a<0>(a, As[1], wm, lane);
    load_b<0>(b, Bs[1], wn, lane);
    STAGE(Ap1, ktA, As[0] + 8192);
    BAR();
    mma16<0, 0>(acc, a, b);
    BAR();
    // ---- p6: (0,1); stage K(2it+2).B0 -> buf0.B0 ----
    load_b<1>(b, Bs[1], wn, lane);
    STAGE(Bp0, ktA, Bs[0]);
    BAR();
    mma16<0, 1>(acc, a, b);
    BAR();
    // ---- p7: (1,1); stage K(2it+3).A0 -> buf1.A0 ----
    load_a<1>(a, As[1], wm, lane);
    STAGE(Ap0, ktB, As[1]);
    BAR();
    mma16<1, 1>(acc, a, b);
    BAR();
    // ---- p8: (1,0); stage K(2it+3).B1 -> buf1.B1; counted vmcnt ----
    load_b<0>(b, Bs[1], wn, lane);
    STAGE(Bp1, ktB, Bs[1] + 8192);
    BAR();
    mma16<1, 0>(acc, a, b);
    VMC4();
    BAR();
  }

  // ---- epilogue: C/D layout col = lane&15, row = (lane>>4)*4 + v ----
  const int rl = lane & 15, rg = lane >> 4;
  float bv[4];
#pragma unroll
  for (int j = 0; j < 4; ++j)
    bv[j] = bias[n0 + (j >> 1) * 128 + wn + (j & 1) * 16 + rl];
#pragma unroll
  for (int i = 0; i < 8; ++i) {
    const int row0 = m0 + (i >> 2) * 128 + wm + (i & 3) * 16 + rg * 4;
#pragma unroll
    for (int j = 0; j < 4; ++j) {
      const int col = n0 + (j >> 1) * 128 + wn + (j & 1) * 16 + rl;
#pragma unroll
      for (int v = 0; v < 4; ++v)
        out[(size_t)(row0 + v) * 4096 + col] = acc[i][j][v] + bv[j];
    }
  }
#undef STAGE
}

// ===========================================================================
extern "C" void kernel_launch(void* const* d_in, const int* in_sizes, int n_in,
                              void* d_out, int out_size, void* d_ws, size_t ws_size,
                              hipStream_t stream) {
  const float* x      = (const float*)d_in[0];
  const int*   codes  = (const int*)d_in[1];
  const float* scales = (const float*)d_in[2];
  const float* th_v   = (const float*)d_in[3];
  const float* th_u   = (const float*)d_in[4];
  const float* lA     = (const float*)d_in[5];
  const float* lB     = (const float*)d_in[6];
  const float* bias   = (const float*)d_in[7];
  float* out = (float*)d_out;

  char* ws = (char*)d_ws;
  float* A2 = (float*)ws;                              // 512 KB
  float* B2 = (float*)(ws + (512u << 10));             // 512 KB
  u16*   Wq = (u16*)(ws + (1u << 20));                 // 32 MB
  u16*   xb = (u16*)(ws + (1u << 20) + (32u << 20));   // 64 MB

  k_rot<<<64, 256, 0, stream>>>(lA, th_v, lB, th_u, A2, B2);
  k_wprime<<<1024, 256, 0, stream>>>(codes, scales, A2, B2, Wq);
  k_xbf16<<<16384, 256, 0, stream>>>(x, xb);
  k_gemm8<<<512, 512, 0, stream>>>(xb, Wq, bias, out);
}

// Round 5
// 355.257 us; speedup vs baseline: 1.4325x; 1.0495x over previous
//
#include <hip/hip_runtime.h>
#include <cstdint>
#include <type_traits>
#include <utility>

// ---------------------------------------------------------------------------
// SOARALinearLayer: out = x @ (W_deq + B2@A2)^T + bias
//   A2 = lora_A @ R_v, B2 = R_u @ lora_B (butterflies folded into LoRA factors)
// => one bf16 MFMA GEMM (M=8192, N=4096, K=4096) + tiny prep.
// R5: (1) keep B0 frags live p1..p4 (p4: zero ds_reads; -14% LDS read traffic)
//     (2) deeper-prefetch stage order, waits vmcnt(8)/(6)/(8)/(6) at p2/4/6/8
//         (min stage->read distance 4 phases, was 2.5)
// ---------------------------------------------------------------------------

typedef unsigned short u16;
typedef unsigned int   u32;
typedef short  s16x8 __attribute__((ext_vector_type(8)));
typedef __bf16 b16x8 __attribute__((ext_vector_type(8)));
typedef float  f32x4 __attribute__((ext_vector_type(4)));
typedef int    i32x4 __attribute__((ext_vector_type(4)));

#define SCALING 1.0f   /* ALPHA/RANK = 32/32 */

__device__ __forceinline__ u16 f2bf(float f) {
  u32 u = __builtin_bit_cast(u32, f);
  u += 0x7FFFu + ((u >> 16) & 1u);
  return (u16)(u >> 16);
}

template <typename T, typename = void>
struct mfma_takes_i16 : std::false_type {};
template <typename T>
struct mfma_takes_i16<T, std::void_t<decltype(__builtin_amdgcn_mfma_f32_16x16x32_bf16(
    std::declval<T>(), std::declval<T>(), std::declval<f32x4>(), 0, 0, 0))>>
    : std::true_type {};

template <typename T>
__device__ __forceinline__ f32x4 mfma_bf16(T a, T b, f32x4 c) {
  if constexpr (mfma_takes_i16<T>::value) {
    return __builtin_amdgcn_mfma_f32_16x16x32_bf16(a, b, c, 0, 0, 0);
  } else {
    return __builtin_amdgcn_mfma_f32_16x16x32_bf16(
        __builtin_bit_cast(b16x8, a), __builtin_bit_cast(b16x8, b), c, 0, 0, 0);
  }
}

__device__ __forceinline__ void gload_lds16(const void* g, void* l) {
  __builtin_amdgcn_global_load_lds((const __attribute__((address_space(1))) u32*)g,
                                   (__attribute__((address_space(3))) u32*)l,
                                   16, 0, 0);
}

// ===========================================================================
// Kernel 1 (merged): blocks 0-31: A2 = lora_A @ R_v ; blocks 32-63: B2 = R_u@B
// ===========================================================================
__global__ __launch_bounds__(256) void k_rot(const float* __restrict__ A,
                                             const float* __restrict__ thA,
                                             const float* __restrict__ B,
                                             const float* __restrict__ thB,
                                             float* __restrict__ A2,
                                             float* __restrict__ B2) {
  __shared__ float buf[4096];
  const int t = threadIdx.x;
  if (blockIdx.x < 32) {
    const int row = blockIdx.x;
    const float* src = A + (size_t)row * 4096;
    for (int p = 0; p < 16; ++p) buf[p * 256 + t] = src[p * 256 + t];
    __syncthreads();
    for (int j = 0; j < 12; ++j) {
      const int k = 4096 >> j;
      const int half = k >> 1;
      const int lh = 11 - j;
      for (int p = 0; p < 8; ++p) {
        int tp = p * 256 + t;
        int b = tp >> lh;
        int i = tp & (half - 1);
        int pi = b * k + i;
        int qi = pi + half;
        float s, c;
        sincosf(thA[j * 2048 + tp], &s, &c);
        float xp = buf[pi], xq = buf[qi];
        buf[pi] = c * xp + s * xq;
        buf[qi] = -s * xp + c * xq;
      }
      __syncthreads();
    }
    for (int p = 0; p < 16; ++p) A2[(size_t)row * 4096 + p * 256 + t] = buf[p * 256 + t];
  } else {
    const int col = blockIdx.x - 32;
    for (int p = 0; p < 16; ++p) buf[p * 256 + t] = B[(size_t)(p * 256 + t) * 32 + col];
    __syncthreads();
    for (int j = 11; j >= 0; --j) {
      const int k = 4096 >> j;
      const int half = k >> 1;
      const int lh = 11 - j;
      for (int p = 0; p < 8; ++p) {
        int tp = p * 256 + t;
        int b = tp >> lh;
        int i = tp & (half - 1);
        int pi = b * k + i;
        int qi = pi + half;
        float s, c;
        sincosf(thB[j * 2048 + tp], &s, &c);
        float xp = buf[pi], xq = buf[qi];
        buf[pi] = c * xp - s * xq;
        buf[qi] = s * xp + c * xq;
      }
      __syncthreads();
    }
    for (int p = 0; p < 16; ++p)
      B2[(size_t)(p * 256 + t) * 32 + col] = SCALING * buf[p * 256 + t];
  }
}

// ===========================================================================
// Kernel 2: W'[n][k] = (codes-8)*scale + sum_r B2[n][r]*A2[r][k], bf16 out.
// 1024 blocks: 32 n-tiles x 32 k-tiles of 128x128. B2 transposed in LDS.
// ===========================================================================
__global__ __launch_bounds__(256) void k_wprime(const int* __restrict__ codes,
                                                const float* __restrict__ scales,
                                                const float* __restrict__ A2,
                                                const float* __restrict__ B2,
                                                u16* __restrict__ Wq) {
  __shared__ float A2s[32][128];
  __shared__ float B2t[32][128];
  const int t = threadIdx.x;
  const int n0 = (blockIdx.x >> 5) << 7;
  const int k0 = (blockIdx.x & 31) << 7;

#pragma unroll
  for (int q = 0; q < 4; ++q) {
    int f = (q * 256 + t) * 4;
    int r = f >> 7, c = f & 127;
    *(f32x4*)&A2s[r][c] = *(const f32x4*)(A2 + (size_t)r * 4096 + k0 + c);
  }
#pragma unroll
  for (int q = 0; q < 4; ++q) {
    int f = (q * 256 + t) * 4;
    int i = f >> 5, r = f & 31;
    f32x4 v = *(const f32x4*)(B2 + (size_t)(n0 + i) * 32 + r);
    B2t[r][i] = v[0]; B2t[r + 1][i] = v[1]; B2t[r + 2][i] = v[2]; B2t[r + 3][i] = v[3];
  }
  __syncthreads();

  const int tr = t >> 4, tc = t & 15;   // 16 x 16 threads; 8 rows x 8 cols each
  const int kg = k0 + tc * 8;
  float acc[8][8];
#pragma unroll
  for (int i = 0; i < 8; ++i) {
    const int n = n0 + tr * 8 + i;
    const float sc = scales[((size_t)n << 6) + (kg >> 6)];
    const i32x4 c0 = *(const i32x4*)(codes + (size_t)n * 4096 + kg);
    const i32x4 c1 = *(const i32x4*)(codes + (size_t)n * 4096 + kg + 4);
#pragma unroll
    for (int e = 0; e < 4; ++e) {
      acc[i][e]     = (float)(c0[e] - 8) * sc;
      acc[i][4 + e] = (float)(c1[e] - 8) * sc;
    }
  }
#pragma unroll
  for (int r = 0; r < 32; ++r) {
    const f32x4 a0 = *(const f32x4*)&A2s[r][tc * 8];
    const f32x4 a1 = *(const f32x4*)&A2s[r][tc * 8 + 4];
    const f32x4 b0 = *(const f32x4*)&B2t[r][tr * 8];
    const f32x4 b1 = *(const f32x4*)&B2t[r][tr * 8 + 4];
#pragma unroll
    for (int i = 0; i < 4; ++i) {
#pragma unroll
      for (int e = 0; e < 4; ++e) {
        acc[i][e]         += b0[i] * a0[e];
        acc[i][4 + e]     += b0[i] * a1[e];
        acc[4 + i][e]     += b1[i] * a0[e];
        acc[4 + i][4 + e] += b1[i] * a1[e];
      }
    }
  }
#pragma unroll
  for (int i = 0; i < 8; ++i) {
    const int n = n0 + tr * 8 + i;
    s16x8 o;
#pragma unroll
    for (int e = 0; e < 8; ++e) o[e] = (short)f2bf(acc[i][e]);
    *(s16x8*)(Wq + (size_t)n * 4096 + kg) = o;
  }
}

// ===========================================================================
// Kernel 3: x (f32) -> bf16
// ===========================================================================
__global__ __launch_bounds__(256) void k_xbf16(const float* __restrict__ x,
                                               u16* __restrict__ xb) {
  const size_t i = ((size_t)blockIdx.x * 256 + threadIdx.x) * 8;
  f32x4 a = *(const f32x4*)(x + i);
  f32x4 b = *(const f32x4*)(x + i + 4);
  s16x8 o;
  o[0] = (short)f2bf(a[0]); o[1] = (short)f2bf(a[1]);
  o[2] = (short)f2bf(a[2]); o[3] = (short)f2bf(a[3]);
  o[4] = (short)f2bf(b[0]); o[5] = (short)f2bf(b[1]);
  o[6] = (short)f2bf(b[2]); o[7] = (short)f2bf(b[3]);
  *(s16x8*)(xb + i) = o;
}

// ===========================================================================
// Main GEMM, 256x256 tile, BK=64, 8-phase counted-vmcnt schedule.
// Stage order (iter it: buf0=K(2it) phases 1-4, buf1=K(2it+1) phases 5-8):
//   S1@p1 -> buf1.B0(2it+1)   S2@p2 -> buf1.A1(2it+1)
//   S3@p3 -> buf0.A0(2it+2)   S4@p4 -> buf0.B1(2it+2)
//   S5@p5 -> buf0.B0(2it+2)   S6@p6 -> buf0.A1(2it+2)
//   S7@p7 -> buf1.A0(2it+3)   S8@p8 -> buf1.B1(2it+3)
// Waits: vmcnt(8)@p2, vmcnt(6)@p4, vmcnt(8)@p6, vmcnt(6)@p8 (derived by
// queue simulation: every read's stage drains >=1 barrier before the read;
// every stage lands >=2 barriers after its region's last ds_read).
// B0 fragments held in regs p1->p4 (p4 has no ds_reads).
// ===========================================================================
#define BAR()    __builtin_amdgcn_s_barrier()
#define VMC(n)   do { asm volatile("s_waitcnt vmcnt(" #n ")" ::: "memory"); \
                      __builtin_amdgcn_sched_barrier(0); } while (0)

template <int QM>
__device__ __forceinline__ void load_a(s16x8 a[4][2], const u16* as, int wm, int lane) {
  const int rl = lane & 15, sl = lane >> 4;
#pragma unroll
  for (int i = 0; i < 4; ++i) {
    const int row = QM * 128 + wm + i * 16 + rl;
#pragma unroll
    for (int kk = 0; kk < 2; ++kk) {
      const int slot = kk * 4 + sl;
      a[i][kk] = *(const s16x8*)(as + row * 64 + ((slot ^ (row & 7)) << 3));
    }
  }
}

template <int QN>
__device__ __forceinline__ void load_b(s16x8 b[2][2], const u16* bs, int wn, int lane) {
  const int rl = lane & 15, sl = lane >> 4;
#pragma unroll
  for (int j = 0; j < 2; ++j) {
    const int row = QN * 128 + wn + j * 16 + rl;
#pragma unroll
    for (int kk = 0; kk < 2; ++kk) {
      const int slot = kk * 4 + sl;
      b[j][kk] = *(const s16x8*)(bs + row * 64 + ((slot ^ (row & 7)) << 3));
    }
  }
}

template <int QM, int QN>
__device__ __forceinline__ void mma16(f32x4 acc[8][4], s16x8 a[4][2], s16x8 b[2][2]) {
  __builtin_amdgcn_s_setprio(1);
#pragma unroll
  for (int kk = 0; kk < 2; ++kk)
#pragma unroll
    for (int i = 0; i < 4; ++i)
#pragma unroll
      for (int j = 0; j < 2; ++j)
        acc[QM * 4 + i][QN * 2 + j] = mfma_bf16(a[i][kk], b[j][kk], acc[QM * 4 + i][QN * 2 + j]);
  __builtin_amdgcn_s_setprio(0);
}

__global__ __launch_bounds__(512, 2) void k_gemm8(const u16* __restrict__ Abf,
                                                  const u16* __restrict__ Bbf,
                                                  const float* __restrict__ bias,
                                                  float* __restrict__ out) {
  __shared__ __align__(16) u16 As[2][256 * 64];
  __shared__ __align__(16) u16 Bs[2][256 * 64];

  const int bid = blockIdx.x;
  const int wg = (bid & 7) * 64 + (bid >> 3);   // 512 % 8 == 0: bijective XCD swizzle
  const int mt = wg >> 4, nt = wg & 15;
  const int m0 = mt << 8, n0 = nt << 8;
  const int tid = threadIdx.x;
  const int lane = tid & 63;
  const int wid = tid >> 6;
  const int wm = (wid >> 2) * 64;   // row sub-offset within each 128-row half
  const int wn = (wid & 3) * 32;    // col sub-offset within each 128-col half

  int rowc[2], swzc[2];
#pragma unroll
  for (int c = 0; c < 2; ++c) {
    const int flat = (c * 512 + tid) * 8;
    rowc[c] = flat >> 6;
    const int slot = (flat >> 3) & 7;
    swzc[c] = (slot ^ (rowc[c] & 7)) << 3;   // inverse-swizzled global source
  }
  const u16* Ap0 = Abf + ((size_t)m0) * 4096;
  const u16* Ap1 = Abf + ((size_t)(m0 + 128)) * 4096;
  const u16* Bp0 = Bbf + ((size_t)n0) * 4096;
  const u16* Bp1 = Bbf + ((size_t)(n0 + 128)) * 4096;

#define STAGE(gpan, kt, ldsbase)                                              \
  do {                                                                        \
    _Pragma("unroll")                                                         \
    for (int c = 0; c < 2; ++c)                                               \
      gload_lds16((gpan) + (size_t)rowc[c] * 4096 + (kt) * 64 + swzc[c],      \
                  (ldsbase) + (c * 512 + tid) * 8);                           \
  } while (0)

  f32x4 acc[8][4] = {};
  s16x8 a[4][2], b0[2][2], b1[2][2];

  // ---- prologue: K0 full -> buf0; K1.A0 -> buf1.A0; K1.B1 -> buf1.B1 ----
  STAGE(Ap0, 0, As[0]);
  STAGE(Ap1, 0, As[0] + 8192);
  STAGE(Bp0, 0, Bs[0]);
  STAGE(Bp1, 0, Bs[0] + 8192);
  STAGE(Ap0, 1, As[1]);
  STAGE(Bp1, 1, Bs[1] + 8192);
  VMC(4);          // buf0 (8 ops) landed; buf1.A0/B1 may remain in flight
  BAR();

#pragma unroll 1
  for (int it = 0; it < 32; ++it) {
    const int kn1 = 2 * it + 1;
    const int ktA = (2 * it + 2 < 64) ? 2 * it + 2 : 63;  // clamped tail (dead stages)
    const int ktB = (2 * it + 3 < 64) ? 2 * it + 3 : 63;

    // ---- p1: (0,0) a0,b0 from buf0; S1: buf1.B0 <- K(2it+1) ----
    load_a<0>(a, As[0], wm, lane);
    load_b<0>(b0, Bs[0], wn, lane);
    STAGE(Bp0, kn1, Bs[1]);
    BAR();
    mma16<0, 0>(acc, a, b0);
    BAR();
    // ---- p2: (0,1) b1 from buf0; S2: buf1.A1 <- K(2it+1); vmcnt(8) ----
    load_b<1>(b1, Bs[0], wn, lane);
    STAGE(Ap1, kn1, As[1] + 8192);
    BAR();
    mma16<0, 1>(acc, a, b1);
    VMC(8);
    BAR();
    // ---- p3: (1,1) a1 from buf0; S3: buf0.A0 <- K(2it+2) ----
    load_a<1>(a, As[0], wm, lane);
    STAGE(Ap0, ktA, As[0]);
    BAR();
    mma16<1, 1>(acc, a, b1);
    BAR();
    // ---- p4: (1,0) uses kept b0 (no ds_reads); S4: buf0.B1; vmcnt(6) ----
    STAGE(Bp1, ktA, Bs[0] + 8192);
    BAR();
    mma16<1, 0>(acc, a, b0);
    VMC(6);
    BAR();
    // ---- p5: (0,0) from buf1; S5: buf0.B0 <- K(2it+2) ----
    load_a<0>(a, As[1], wm, lane);
    load_b<0>(b0, Bs[1], wn, lane);
    STAGE(Bp0, ktA, Bs[0]);
    BAR();
    mma16<0, 0>(acc, a, b0);
    BAR();
    // ---- p6: (0,1) from buf1; S6: buf0.A1 <- K(2it+2); vmcnt(8) ----
    load_b<1>(b1, Bs[1], wn, lane);
    STAGE(Ap1, ktA, As[0] + 8192);
    BAR();
    mma16<0, 1>(acc, a, b1);
    VMC(8);
    BAR();
    // ---- p7: (1,1) from buf1; S7: buf1.A0 <- K(2it+3) ----
    load_a<1>(a, As[1], wm, lane);
    STAGE(Ap0, ktB, As[1]);
    BAR();
    mma16<1, 1>(acc, a, b1);
    BAR();
    // ---- p8: (1,0) kept b0 (no ds_reads); S8: buf1.B1; vmcnt(6) ----
    STAGE(Bp1, ktB, Bs[1] + 8192);
    BAR();
    mma16<1, 0>(acc, a, b0);
    VMC(6);
    BAR();
  }

  // ---- epilogue: C/D layout col = lane&15, row = (lane>>4)*4 + v ----
  const int rl = lane & 15, rg = lane >> 4;
  float bv[4];
#pragma unroll
  for (int j = 0; j < 4; ++j)
    bv[j] = bias[n0 + (j >> 1) * 128 + wn + (j & 1) * 16 + rl];
#pragma unroll
  for (int i = 0; i < 8; ++i) {
    const int row0 = m0 + (i >> 2) * 128 + wm + (i & 3) * 16 + rg * 4;
#pragma unroll
    for (int j = 0; j < 4; ++j) {
      const int col = n0 + (j >> 1) * 128 + wn + (j & 1) * 16 + rl;
#pragma unroll
      for (int v = 0; v < 4; ++v)
        out[(size_t)(row0 + v) * 4096 + col] = acc[i][j][v] + bv[j];
    }
  }
#undef STAGE
}

// ===========================================================================
extern "C" void kernel_launch(void* const* d_in, const int* in_sizes, int n_in,
                              void* d_out, int out_size, void* d_ws, size_t ws_size,
                              hipStream_t stream) {
  const float* x      = (const float*)d_in[0];
  const int*   codes  = (const int*)d_in[1];
  const float* scales = (const float*)d_in[2];
  const float* th_v   = (const float*)d_in[3];
  const float* th_u   = (const float*)d_in[4];
  const float* lA     = (const float*)d_in[5];
  const float* lB     = (const float*)d_in[6];
  const float* bias   = (const float*)d_in[7];
  float* out = (float*)d_out;

  char* ws = (char*)d_ws;
  float* A2 = (float*)ws;                              // 512 KB
  float* B2 = (float*)(ws + (512u << 10));             // 512 KB
  u16*   Wq = (u16*)(ws + (1u << 20));                 // 32 MB
  u16*   xb = (u16*)(ws + (1u << 20) + (32u << 20));   // 64 MB

  k_rot<<<64, 256, 0, stream>>>(lA, th_v, lB, th_u, A2, B2);
  k_wprime<<<1024, 256, 0, stream>>>(codes, scales, A2, B2, Wq);
  k_xbf16<<<16384, 256, 0, stream>>>(x, xb);
  k_gemm8<<<512, 512, 0, stream>>>(xb, Wq, bias, out);
}